// Round 2
// 776.462 us; speedup vs baseline: 1.4378x; 1.4378x over previous
//
#include <hip/hip_runtime.h>
#include <hip/hip_bf16.h>

#define NB 1024
#define NT 256
#define NC 512
#define NH 64

typedef __attribute__((ext_vector_type(8))) short bf16x8;   // 8 bf16 (4 VGPRs)
typedef __attribute__((ext_vector_type(4))) float f32x4;
typedef __attribute__((ext_vector_type(4))) short s16x4;
typedef __attribute__((ext_vector_type(4))) int   i32x4;

__device__ __forceinline__ short f2bf(float f) {
    unsigned u = __builtin_bit_cast(unsigned, f);
    u = (u + 0x7FFFu + ((u >> 16) & 1u)) >> 16;   // RNE
    return (short)u;
}

__device__ __forceinline__ bf16x8 cvt8(f32x4 a0, f32x4 a1) {
#if defined(__has_builtin) && __has_builtin(__builtin_amdgcn_cvt_pk_bf16_f32)
    i32x4 pk;
    pk[0] = __builtin_bit_cast(int, __builtin_amdgcn_cvt_pk_bf16_f32(a0[0], a0[1]));
    pk[1] = __builtin_bit_cast(int, __builtin_amdgcn_cvt_pk_bf16_f32(a0[2], a0[3]));
    pk[2] = __builtin_bit_cast(int, __builtin_amdgcn_cvt_pk_bf16_f32(a1[0], a1[1]));
    pk[3] = __builtin_bit_cast(int, __builtin_amdgcn_cvt_pk_bf16_f32(a1[2], a1[3]));
    return __builtin_bit_cast(bf16x8, pk);
#else
    bf16x8 r;
    r[0] = f2bf(a0[0]); r[1] = f2bf(a0[1]); r[2] = f2bf(a0[2]); r[3] = f2bf(a0[3]);
    r[4] = f2bf(a1[0]); r[5] = f2bf(a1[1]); r[6] = f2bf(a1[2]); r[7] = f2bf(a1[3]);
    return r;
#endif
}

// Kernel 0: swizzle Wq|Wk|Wv (fp32 [512,64]) into grouped bf16 B-fragment layout.
// Shorts index: g2*32768 + c*2048 + tgi*512 + quad*128 + l16*8 + j
//   value = W_{g2}[k = c*32 + quad*8 + j][h = tgi*16 + l16],  g2: 0=q 1=k 2=v
__global__ void swzw(const float* __restrict__ Wq, const float* __restrict__ Wk,
                     const float* __restrict__ Wv, short* __restrict__ wsw) {
    int tid = blockIdx.x * 256 + threadIdx.x;    // 98304 total
    int j    = tid & 7;
    int l16  = (tid >> 3) & 15;
    int quad = (tid >> 7) & 3;
    int tgi  = (tid >> 9) & 3;
    int c    = (tid >> 11) & 15;
    int g2   = tid >> 15;                        // 0..2
    const float* W = (g2 == 0) ? Wq : (g2 == 1) ? Wk : Wv;
    int h = tgi * 16 + l16;
    int k = c * 32 + quad * 8 + j;
    wsw[tid] = f2bf(W[k * NH + h]);
}

// LDS (shorts), 72 KB total -> 2 blocks/CU:
//   [0,4096)      per-wave scratch, 512 shorts each (q transpose + P^T chunks)
//   [4096,20480)  K frag swizzle:  4096 + (row>>4)*1024 + (h>>5)*512 + ((h>>3)&3)*128 + (row&15)*8 + (h&7)
//   [20480,36864) V frag swizzle: 20480 + (row>>5)*2048 + (h>>4)*512 + ((row>>3)&3)*128 + (h&15)*8 + (row&7)
__global__ __launch_bounds__(512, 4)
void attn_fused(const float* __restrict__ x, const short* __restrict__ wsw,
                float* __restrict__ out) {
    __shared__ short lds[36864];   // 72 KB
    const int b    = blockIdx.x;
    const int tid  = threadIdx.x;
    const int w    = tid >> 6;     // wave 0..7
    const int lane = tid & 63;
    const int l16  = lane & 15;
    const int quad = lane >> 4;

    const float* xb = x + (size_t)b * NT * NC;
    const int rts[2] = { w, 15 - w };   // balanced causal load: (w+1)+(16-w) = 17

    short* pbw = lds + w * 512;          // per-wave 1 KB scratch
    const short* kb = lds + 4096;
    const short* vb = lds + 20480;

    bf16x8 qf[2][2];   // per-wave q fragments, built in Phase A, used in Phase B

    // ---------------- Phase A: row-owned fused QKV projection ----------------
    // Wave w projects ALL 192 cols for its 2 row-tiles {w, 15-w}.  q stays in
    // registers (via private scratch transpose); k,v scatter into shared LDS.
    #pragma unroll
    for (int i = 0; i < 2; ++i) {
        const int R = rts[i];
        const float* xp = xb + (size_t)(R * 16 + l16) * NC + quad * 8;  // lane's row
        const short* wq = wsw + lane * 8;

        f32x4 acc[12];
        #pragma unroll
        for (int t = 0; t < 12; ++t) acc[t] = (f32x4){0.f, 0.f, 0.f, 0.f};

        f32x4 xa[2][2];   // double-buffered x chunk (16 rows x 32 floats)
        xa[0][0] = *(const f32x4*)xp;
        xa[0][1] = *(const f32x4*)(xp + 4);

        #pragma unroll 2
        for (int c = 0; c < 16; ++c) {
            const int cur = c & 1;
            if (c < 15) {   // prefetch next k-chunk
                const float* pn = xp + (c + 1) * 32;
                xa[cur ^ 1][0] = *(const f32x4*)pn;
                xa[cur ^ 1][1] = *(const f32x4*)(pn + 4);
            }
            const short* wc = wq + c * 2048;
            bf16x8 af = cvt8(xa[cur][0], xa[cur][1]);
            // staggered B-frag loads: 4 live at a time, issued just before use
            {
                bf16x8 b0 = *(const bf16x8*)(wc);
                bf16x8 b1 = *(const bf16x8*)(wc + 512);
                bf16x8 b2 = *(const bf16x8*)(wc + 1024);
                bf16x8 b3 = *(const bf16x8*)(wc + 1536);
                acc[0] = __builtin_amdgcn_mfma_f32_16x16x32_bf16(af, b0, acc[0], 0, 0, 0);
                acc[1] = __builtin_amdgcn_mfma_f32_16x16x32_bf16(af, b1, acc[1], 0, 0, 0);
                acc[2] = __builtin_amdgcn_mfma_f32_16x16x32_bf16(af, b2, acc[2], 0, 0, 0);
                acc[3] = __builtin_amdgcn_mfma_f32_16x16x32_bf16(af, b3, acc[3], 0, 0, 0);
            }
            {
                bf16x8 b4 = *(const bf16x8*)(wc + 32768);
                bf16x8 b5 = *(const bf16x8*)(wc + 33280);
                bf16x8 b6 = *(const bf16x8*)(wc + 33792);
                bf16x8 b7 = *(const bf16x8*)(wc + 34304);
                acc[4] = __builtin_amdgcn_mfma_f32_16x16x32_bf16(af, b4, acc[4], 0, 0, 0);
                acc[5] = __builtin_amdgcn_mfma_f32_16x16x32_bf16(af, b5, acc[5], 0, 0, 0);
                acc[6] = __builtin_amdgcn_mfma_f32_16x16x32_bf16(af, b6, acc[6], 0, 0, 0);
                acc[7] = __builtin_amdgcn_mfma_f32_16x16x32_bf16(af, b7, acc[7], 0, 0, 0);
            }
            {
                bf16x8 b8  = *(const bf16x8*)(wc + 65536);
                bf16x8 b9  = *(const bf16x8*)(wc + 66048);
                bf16x8 b10 = *(const bf16x8*)(wc + 66560);
                bf16x8 b11 = *(const bf16x8*)(wc + 67072);
                acc[8]  = __builtin_amdgcn_mfma_f32_16x16x32_bf16(af, b8,  acc[8],  0, 0, 0);
                acc[9]  = __builtin_amdgcn_mfma_f32_16x16x32_bf16(af, b9,  acc[9],  0, 0, 0);
                acc[10] = __builtin_amdgcn_mfma_f32_16x16x32_bf16(af, b10, acc[10], 0, 0, 0);
                acc[11] = __builtin_amdgcn_mfma_f32_16x16x32_bf16(af, b11, acc[11], 0, 0, 0);
            }
        }

        // ---- q (tg 0..3): fold softmax scale, transpose C-layout -> B-frag via
        //      private scratch, two 32-col half-passes (intra-wave DS ordering).
        #pragma unroll
        for (int hh = 0; hh < 2; ++hh) {
            #pragma unroll
            for (int t2 = 0; t2 < 2; ++t2) {
                const f32x4 a = acc[hh * 2 + t2];
                #pragma unroll
                for (int r = 0; r < 4; ++r)
                    pbw[(quad * 4 + r) * 32 + t2 * 16 + l16] = f2bf(a[r] * 0.125f);
            }
            qf[i][hh] = *(const bf16x8*)(pbw + l16 * 32 + quad * 8);
        }
        // ---- k (tg 4..7): scatter into swizzled K region ----
        #pragma unroll
        for (int t2 = 0; t2 < 4; ++t2) {
            const int h = t2 * 16 + l16;
            const int koff = 4096 + R * 1024 + (h >> 5) * 512 + ((h >> 3) & 3) * 128 + (h & 7);
            const f32x4 a = acc[4 + t2];
            #pragma unroll
            for (int r = 0; r < 4; ++r)
                lds[koff + (quad * 4 + r) * 8] = f2bf(a[r]);
        }
        // ---- v (tg 8..11): scatter into swizzled V region ----
        #pragma unroll
        for (int t2 = 0; t2 < 4; ++t2) {
            const int h = t2 * 16 + l16;
            const f32x4 a = acc[8 + t2];
            #pragma unroll
            for (int r = 0; r < 4; ++r) {
                const int row = R * 16 + quad * 4 + r;
                lds[20480 + (row >> 5) * 2048 + (h >> 4) * 512 + ((row >> 3) & 3) * 128
                    + (h & 15) * 8 + (row & 7)] = f2bf(a[r]);
            }
        }
    }
    __syncthreads();   // K,V visible to all waves; q already in registers

    // ---------------- Phase B: causal attention, S^T formulation ----------------
    // S^T = K·Q^T via mfma(A=kf, B=qf).  D[m=s_local][n=t_local]: lane l16 = t,
    // regs span s.  Softmax over s: 4 parallel in-lane chains + 2 cross-quad shuffles.
    #pragma unroll
    for (int i = 0; i < 2; ++i) {
        const int R = rts[i];
        f32x4 sacc[16];
        #pragma unroll
        for (int ct = 0; ct < 16; ++ct) sacc[ct] = (f32x4){0.f, 0.f, 0.f, 0.f};

        #pragma unroll
        for (int ct = 0; ct < 16; ++ct) {
            if (ct <= R) {
                #pragma unroll
                for (int c = 0; c < 2; ++c) {
                    bf16x8 kf = *(const bf16x8*)(kb + ct * 1024 + c * 512 + quad * 128 + l16 * 8);
                    sacc[ct] = __builtin_amdgcn_mfma_f32_16x16x32_bf16(kf, qf[i][c], sacc[ct], 0, 0, 0);
                }
                if (ct == R) {   // causal: mask s_local > t_local
                    #pragma unroll
                    for (int r = 0; r < 4; ++r)
                        if (quad * 4 + r > l16) sacc[ct][r] = -1e30f;
                }
            }
        }

        // softmax over s: 4 independent chains (depth<=16), then cross-quad
        f32x4 mm = (f32x4){-1e30f, -1e30f, -1e30f, -1e30f};
        #pragma unroll
        for (int ct = 0; ct < 16; ++ct)
            if (ct <= R) {
                #pragma unroll
                for (int r = 0; r < 4; ++r) mm[r] = fmaxf(mm[r], sacc[ct][r]);
            }
        float m0 = fmaxf(fmaxf(mm[0], mm[1]), fmaxf(mm[2], mm[3]));
        m0 = fmaxf(m0, __shfl_xor(m0, 16));
        m0 = fmaxf(m0, __shfl_xor(m0, 32));

        f32x4 lsv = (f32x4){0.f, 0.f, 0.f, 0.f};
        #pragma unroll
        for (int ct = 0; ct < 16; ++ct)
            if (ct <= R) {
                #pragma unroll
                for (int r = 0; r < 4; ++r) {
                    float p = __expf(sacc[ct][r] - m0);
                    sacc[ct][r] = p;
                    lsv[r] += p;
                }
            }
        float ls = (lsv[0] + lsv[1]) + (lsv[2] + lsv[3]);
        ls += __shfl_xor(ls, 16);
        ls += __shfl_xor(ls, 32);

        // O^T = V^T · P^T, chunked P^T through per-wave 1 KB scratch
        f32x4 oacc[4];
        #pragma unroll
        for (int ot = 0; ot < 4; ++ot) oacc[ot] = (f32x4){0.f, 0.f, 0.f, 0.f};

        #pragma unroll
        for (int c2 = 0; c2 < 8; ++c2) {
            if (c2 <= (R >> 1)) {
                #pragma unroll
                for (int half = 0; half < 2; ++half) {
                    int ct = 2 * c2 + half;
                    s16x4 vals;
                    if (ct <= R) {
                        #pragma unroll
                        for (int r = 0; r < 4; ++r) vals[r] = f2bf(sacc[ct][r]);
                    } else {
                        vals = (s16x4){0, 0, 0, 0};
                    }
                    // P^T[s=32c2+16*half+quad*4+r][t=l16]
                    *(s16x4*)(pbw + l16 * 32 + half * 16 + quad * 4) = vals;
                }
                bf16x8 pf = *(const bf16x8*)(pbw + l16 * 32 + quad * 8);
                #pragma unroll
                for (int ot = 0; ot < 4; ++ot) {
                    bf16x8 vf = *(const bf16x8*)(vb + c2 * 2048 + ot * 512 + quad * 128 + l16 * 8);
                    oacc[ot] = __builtin_amdgcn_mfma_f32_16x16x32_bf16(vf, pf, oacc[ot], 0, 0, 0);
                }
            }
        }

        // O^T C-layout: lane l16 = t_local (ls lane-uniform across regs),
        // regs = h = ot*16 + quad*4 + r
        float inv = 1.0f / ls;
        float* ob = out + ((size_t)b * NT + R * 16 + l16) * NH;
        #pragma unroll
        for (int ot = 0; ot < 4; ++ot) {
            f32x4 o;
            #pragma unroll
            for (int r = 0; r < 4; ++r) o[r] = oacc[ot][r] * inv;
            *(f32x4*)(ob + ot * 16 + quad * 4) = o;
        }
    }
}

extern "C" void kernel_launch(void* const* d_in, const int* in_sizes, int n_in,
                              void* d_out, int out_size, void* d_ws, size_t ws_size,
                              hipStream_t stream) {
    const float* x  = (const float*)d_in[0];
    const float* Wq = (const float*)d_in[1];
    const float* Wk = (const float*)d_in[2];
    const float* Wv = (const float*)d_in[3];
    float* outp = (float*)d_out;
    short* wsw  = (short*)d_ws;    // 98304 shorts = 192 KB

    swzw<<<384, 256, 0, stream>>>(Wq, Wk, Wv, wsw);
    attn_fused<<<NB, 512, 0, stream>>>(x, wsw, outp);
}